// Round 3
// baseline (727.689 us; speedup 1.0000x reference)
//
#include <hip/hip_runtime.h>
#include <math.h>

#define B_ 8
#define D_ 1024
#define HW_ 4096
#define NH_ 16
#define EPS_ 1e-5f

// workspace offsets (floats) — total 9,150,592 floats = 36.6 MB
#define PE_OFF   0u          // 4096*1024   pe[d][p]
#define UT_OFF   4194304u    // B*D*NH      u_t[b][d][h] (scale folded)
#define TB_OFF   4325376u    // B*D
#define SCP_OFF  4333568u    // 8 slices * B*NH*HW partial scores; probs land in slice 0
#define SP_OFF   8527872u    // 8 * B*HW  partial sums
#define QP_OFF   8790016u    // 8 * B*HW  partial sumsq
#define WP_OFF   8527872u    // 4 * B*NH*D  (overlays sp/qp after k_stats)
#define Q0_OFF   9052160u    // B*D
#define VCLS_OFF 9060352u    // B*D
#define P0_OFF   9068544u    // B*NH
#define MU_OFF   9068672u    // B*HW
#define RS_OFF   9101440u    // B*HW
#define CLS_OFF  9134208u    // B*D
#define R0_OFF   9142400u    // B*D

// ---------------- K0: positional encoding table, pe[d][p] -------------------
__global__ void k_pe(float* __restrict__ pe) {
    int idx = blockIdx.x * 256 + threadIdx.x;
    int p  = idx & (HW_ - 1);
    int dp = idx >> 12;                          // d-pair 0..511
    float e = (float)(2 * dp);
    float rate = exp2f(e * (-13.287712379549449f / 1024.0f)); // 10000^(-e/1024)
    float ang = (float)p * rate;
    float s, c;
    sincosf(ang, &s, &c);
    pe[(size_t)(2 * dp) * HW_ + p]     = s;
    pe[(size_t)(2 * dp + 1) * HW_ + p] = c;
}

// ---------------- K1: q0[b,:] and v_cls[b,:] --------------------------------
__global__ void k_qv(const float* __restrict__ Wqkv, const float* __restrict__ bqkv,
                     const float* __restrict__ ctx,
                     float* __restrict__ q0, float* __restrict__ vcls) {
    int wid  = (blockIdx.x * 256 + threadIdx.x) >> 6;
    int lane = threadIdx.x & 63;
    int isv  = wid >> 13;
    int r    = wid & 8191;
    int b = r >> 10, i = r & 1023;
    int row = isv ? (2 * D_ + i) : i;
    const float4* wr = (const float4*)(Wqkv + (size_t)row * D_);
    const float4* cb = (const float4*)(ctx + b * D_);
    float acc = 0.0f;
    for (int k = lane; k < 256; k += 64) {
        float4 a = wr[k], c = cb[k];
        acc += a.x * c.x + a.y * c.y + a.z * c.z + a.w * c.w;
    }
    for (int o = 32; o; o >>= 1) acc += __shfl_down(acc, o);
    if (lane == 0) {
        float v = acc + bqkv[row];
        if (isv) vcls[b * D_ + i] = v; else q0[b * D_ + i] = v;
    }
}

// ---------------- K2: u_t[b][d][h] (scale folded) and t_b[b][i] -------------
__global__ void k_u_tb(const float* __restrict__ Wqkv,
                       const float* __restrict__ Wo, const float* __restrict__ bo,
                       const float* __restrict__ q0, const float* __restrict__ vcls,
                       float* __restrict__ u_t, float* __restrict__ t_b) {
    if (blockIdx.x < 128) {
        int b = blockIdx.x >> 4, h = blockIdx.x & 15;
        int t = threadIdx.x;
        float a0 = 0, a1 = 0, a2 = 0, a3 = 0;
        const float* q0h = q0 + b * D_ + h * 64;
        for (int j = 0; j < 64; ++j) {
            float qj = q0h[j];
            const float* wr = Wqkv + (size_t)(D_ + h * 64 + j) * D_;
            a0 += qj * wr[t];
            a1 += qj * wr[t + 256];
            a2 += qj * wr[t + 512];
            a3 += qj * wr[t + 768];
        }
        float* ub = u_t + (size_t)(b * D_) * NH_ + h;
        ub[(size_t)t * 16]          = 0.125f * a0;
        ub[(size_t)(t + 256) * 16]  = 0.125f * a1;
        ub[(size_t)(t + 512) * 16]  = 0.125f * a2;
        ub[(size_t)(t + 768) * 16]  = 0.125f * a3;
    } else {
        int wid  = (blockIdx.x - 128) * 4 + (threadIdx.x >> 6);
        int lane = threadIdx.x & 63;
        int b = wid >> 10, i = wid & 1023;
        const float4* wr = (const float4*)(Wo + (size_t)i * D_);
        const float4* vb = (const float4*)(vcls + b * D_);
        float acc = 0.0f;
        for (int k = lane; k < 256; k += 64) {
            float4 a = wr[k], c = vb[k];
            acc += a.x * c.x + a.y * c.y + a.z * c.z + a.w * c.w;
        }
        for (int o = 32; o; o >>= 1) acc += __shfl_down(acc, o);
        if (lane == 0) t_b[b * D_ + i] = acc + bo[i];
    }
}

#define FMA4(A, U) { (A).x += (U) * xc.x; (A).y += (U) * xc.y; \
                     (A).z += (U) * xc.z; (A).w += (U) * xc.w; }

// ------- KA: partial scores + partial LN stats ------------------------------
// grid (16 p-tiles x 8 d-slices, B), block 256 (4 waves). Wave: 32 d-rows,
// lane: 4 p (float4). Partials per d-slice of 128.
__global__ __launch_bounds__(256, 4) void k_scores2(
        const float* __restrict__ x, const float* __restrict__ pe,
        const float* __restrict__ u_t, const float* __restrict__ t_b,
        float* __restrict__ scp, float* __restrict__ sp, float* __restrict__ qp) {
    int tid = threadIdx.x;
    int wave = tid >> 6, lane = tid & 63;
    int b = blockIdx.y;
    int ptile = (blockIdx.x & 15) * 256;
    int ds = blockIdx.x >> 4;          // 0..7
    int p0 = ptile + lane * 4;
    int dbeg = ds * 128 + wave * 32;
    const float* xb  = x  + (size_t)b * D_ * HW_ + p0;
    const float* peb = pe + p0;
    const float* tb  = t_b + b * D_;
    float4 acc[16];
    #pragma unroll
    for (int h = 0; h < 16; ++h) acc[h] = make_float4(0.f, 0.f, 0.f, 0.f);
    float4 s4 = make_float4(0.f, 0.f, 0.f, 0.f);
    float4 q4 = make_float4(0.f, 0.f, 0.f, 0.f);
    #pragma unroll 4
    for (int i = 0; i < 32; ++i) {
        int d = dbeg + i;
        float4 xv = *(const float4*)(xb  + (size_t)d * HW_);
        float4 pv = *(const float4*)(peb + (size_t)d * HW_);
        float4 xc = make_float4(xv.x + pv.x, xv.y + pv.y, xv.z + pv.z, xv.w + pv.w);
        float tbd = tb[d];
        float4 r = make_float4(xc.x + tbd, xc.y + tbd, xc.z + tbd, xc.w + tbd);
        s4.x += r.x; s4.y += r.y; s4.z += r.z; s4.w += r.w;
        q4.x += r.x * r.x; q4.y += r.y * r.y; q4.z += r.z * r.z; q4.w += r.w * r.w;
        const float4* up = (const float4*)(u_t + ((size_t)(b * D_ + d) << 4));
        float4 u0 = up[0], u1 = up[1], u2 = up[2], u3 = up[3];
        FMA4(acc[0],  u0.x) FMA4(acc[1],  u0.y) FMA4(acc[2],  u0.z) FMA4(acc[3],  u0.w)
        FMA4(acc[4],  u1.x) FMA4(acc[5],  u1.y) FMA4(acc[6],  u1.z) FMA4(acc[7],  u1.w)
        FMA4(acc[8],  u2.x) FMA4(acc[9],  u2.y) FMA4(acc[10], u2.z) FMA4(acc[11], u2.w)
        FMA4(acc[12], u3.x) FMA4(acc[13], u3.y) FMA4(acc[14], u3.z) FMA4(acc[15], u3.w)
    }
    __shared__ float red[4][4][256];   // 16 KB
    #pragma unroll 1
    for (int c = 0; c < 4; ++c) {
        if (c) __syncthreads();
        #pragma unroll
        for (int j = 0; j < 4; ++j)
            *(float4*)&red[wave][j][lane * 4] = acc[c * 4 + j];
        __syncthreads();
        #pragma unroll
        for (int j = 0; j < 4; ++j) {
            float s = red[0][j][tid] + red[1][j][tid] + red[2][j][tid] + red[3][j][tid];
            scp[(size_t)ds * 524288 + (size_t)(b * 16 + c * 4 + j) * HW_ + ptile + tid] = s;
        }
    }
    __syncthreads();
    *(float4*)&red[wave][0][lane * 4] = s4;
    *(float4*)&red[wave][1][lane * 4] = q4;
    __syncthreads();
    float S = red[0][0][tid] + red[1][0][tid] + red[2][0][tid] + red[3][0][tid];
    float Q = red[0][1][tid] + red[1][1][tid] + red[2][1][tid] + red[3][1][tid];
    sp[ds * 32768 + b * HW_ + ptile + tid] = S;
    qp[ds * 32768 + b * HW_ + ptile + tid] = Q;
}

// ---------------- K-stats: reduce partial sums -> mu, rstd ------------------
__global__ void k_stats(const float* __restrict__ sp, const float* __restrict__ qp,
                        float* __restrict__ mu_o, float* __restrict__ rs_o) {
    int i = blockIdx.x * 256 + threadIdx.x;  // 0..32767 = b*HW + p
    float S = 0.f, Q = 0.f;
    #pragma unroll
    for (int ds = 0; ds < 8; ++ds) { S += sp[ds * 32768 + i]; Q += qp[ds * 32768 + i]; }
    float mu = S * (1.0f / 1024.0f);
    float var = Q * (1.0f / 1024.0f) - mu * mu;
    mu_o[i] = mu;
    rs_o[i] = rsqrtf(var + EPS_);
}

// ---------------- KB: softmax over 4097 (sums 8 score partials, in-place) ---
__global__ void k_softmax2(float* __restrict__ scp, const float* __restrict__ u_t,
                           const float* __restrict__ ctx, float* __restrict__ probs0) {
    int b = blockIdx.x >> 4, h = blockIdx.x & 15;
    int t = threadIdx.x;  // 256
    __shared__ float lds[256];
    float part = 0.0f;
    for (int d = t; d < D_; d += 256)
        part += u_t[(size_t)(b * D_ + d) * 16 + h] * ctx[b * D_ + d];
    lds[t] = part; __syncthreads();
    for (int o = 128; o; o >>= 1) { if (t < o) lds[t] += lds[t + o]; __syncthreads(); }
    float s0 = lds[0];
    __syncthreads();
    size_t row = (size_t)(b * 16 + h) * HW_;
    float4 v[4];
    float m = s0;
    #pragma unroll
    for (int k = 0; k < 4; ++k) {
        float4 vk = make_float4(0.f, 0.f, 0.f, 0.f);
        #pragma unroll
        for (int ds = 0; ds < 8; ++ds) {
            float4 pvk = ((const float4*)(scp + (size_t)ds * 524288 + row))[t + 256 * k];
            vk.x += pvk.x; vk.y += pvk.y; vk.z += pvk.z; vk.w += pvk.w;
        }
        v[k] = vk;
        m = fmaxf(m, fmaxf(fmaxf(vk.x, vk.y), fmaxf(vk.z, vk.w)));
    }
    lds[t] = m; __syncthreads();
    for (int o = 128; o; o >>= 1) { if (t < o) lds[t] = fmaxf(lds[t], lds[t + o]); __syncthreads(); }
    m = lds[0];
    __syncthreads();
    float zs = 0.0f;
    #pragma unroll
    for (int k = 0; k < 4; ++k) {
        v[k].x = expf(v[k].x - m); v[k].y = expf(v[k].y - m);
        v[k].z = expf(v[k].z - m); v[k].w = expf(v[k].w - m);
        zs += v[k].x + v[k].y + v[k].z + v[k].w;
    }
    float e0 = expf(s0 - m);
    lds[t] = zs; __syncthreads();
    for (int o = 128; o; o >>= 1) { if (t < o) lds[t] += lds[t + o]; __syncthreads(); }
    float inv = 1.0f / (lds[0] + e0);
    float4* pr = (float4*)(scp + row);   // probs overwrite slice-0 partials
    #pragma unroll
    for (int k = 0; k < 4; ++k) {
        float4 o4 = v[k];
        o4.x *= inv; o4.y *= inv; o4.z *= inv; o4.w *= inv;
        pr[t + 256 * k] = o4;
    }
    if (t == 0) probs0[b * 16 + h] = e0 * inv;
}

// ------- KC: fused w-accumulate (p-split 4x) + LN feature-map write ---------
// grid (64 d-groups * 4 p-chunks, B), block 256. Wave: 4 d-rows, lane: float4 p.
__global__ __launch_bounds__(256, 4) void k_wacc3(
        const float* __restrict__ x, const float* __restrict__ pe,
        const float* __restrict__ probs, const float* __restrict__ p0v,
        const float* __restrict__ ctx, const float* __restrict__ t_b,
        const float* __restrict__ mu_i, const float* __restrict__ rs_i,
        const float* __restrict__ gamma, const float* __restrict__ beta,
        float* __restrict__ wp, float* __restrict__ out) {
    int wave = threadIdx.x >> 6, lane = threadIdx.x & 63;
    int b = blockIdx.y;
    int dgrp = blockIdx.x >> 2, pc = blockIdx.x & 3;
    int d0 = (dgrp * 4 + wave) * 4;
    int pbase = pc * 1024;
    const float* xb = x + (size_t)b * D_ * HW_;
    const float* pb = probs + (size_t)b * 16 * HW_;
    float* ob = out + (size_t)b * D_ * HW_;
    float tbv[4], gv[4], bev[4];
    #pragma unroll
    for (int r = 0; r < 4; ++r) {
        tbv[r] = t_b[b * D_ + d0 + r];
        gv[r]  = gamma[d0 + r];
        bev[r] = beta[d0 + r];
    }
    float acc[4][16];
    #pragma unroll
    for (int r = 0; r < 4; ++r)
        #pragma unroll
        for (int h = 0; h < 16; ++h) acc[r][h] = 0.f;
    #pragma unroll 1
    for (int it = 0; it < 4; ++it) {
        int p = pbase + it * 256 + lane * 4;
        float4 xc4[4];
        #pragma unroll
        for (int r = 0; r < 4; ++r) {
            float4 xv = *(const float4*)(xb + (size_t)(d0 + r) * HW_ + p);
            float4 pv = *(const float4*)(pe + (size_t)(d0 + r) * HW_ + p);
            xc4[r].x = xv.x + pv.x; xc4[r].y = xv.y + pv.y;
            xc4[r].z = xv.z + pv.z; xc4[r].w = xv.w + pv.w;
        }
        float4 m4 = *(const float4*)(mu_i + b * HW_ + p);
        float4 r4 = *(const float4*)(rs_i + b * HW_ + p);
        #pragma unroll
        for (int r = 0; r < 4; ++r) {
            float4 o4;
            o4.x = (xc4[r].x + tbv[r] - m4.x) * r4.x * gv[r] + bev[r];
            o4.y = (xc4[r].y + tbv[r] - m4.y) * r4.y * gv[r] + bev[r];
            o4.z = (xc4[r].z + tbv[r] - m4.z) * r4.z * gv[r] + bev[r];
            o4.w = (xc4[r].w + tbv[r] - m4.w) * r4.w * gv[r] + bev[r];
            *(float4*)(ob + (size_t)(d0 + r) * HW_ + p) = o4;
        }
        #pragma unroll
        for (int h = 0; h < 16; ++h) {
            float4 pr = *(const float4*)(pb + (size_t)h * HW_ + p);
            #pragma unroll
            for (int r = 0; r < 4; ++r)
                acc[r][h] += pr.x * xc4[r].x + pr.y * xc4[r].y +
                             pr.z * xc4[r].z + pr.w * xc4[r].w;
        }
    }
    #pragma unroll
    for (int r = 0; r < 4; ++r)
        #pragma unroll
        for (int h = 0; h < 16; ++h) {
            float v = acc[r][h];
            for (int o = 32; o; o >>= 1) v += __shfl_down(v, o);
            acc[r][h] = v;
        }
    if (lane == 0) {
        #pragma unroll
        for (int h = 0; h < 16; ++h) {
            float extra = (pc == 0) ? p0v[b * 16 + h] : 0.f;
            #pragma unroll
            for (int r = 0; r < 4; ++r)
                wp[(size_t)pc * 131072 + (size_t)(b * 16 + h) * D_ + d0 + r] =
                    acc[r][h] + extra * ctx[b * D_ + d0 + r];
        }
    }
}

// ---------------- K7a: cls[b][i] = Wv[i,:] . (sum_pc wp) + bv ---------------
__global__ void k_cls2(const float* __restrict__ Wqkv, const float* __restrict__ bqkv,
                       const float* __restrict__ wp, float* __restrict__ cls) {
    int wid  = (blockIdx.x * 256 + threadIdx.x) >> 6;
    int lane = threadIdx.x & 63;
    int b = wid >> 10, i = wid & 1023, h = i >> 6;
    const float4* wr = (const float4*)(Wqkv + (size_t)(2 * D_ + i) * D_);
    const float4* w0 = (const float4*)(wp + (size_t)(b * 16 + h) * D_);
    float acc = 0.0f;
    for (int k = lane; k < 256; k += 64) {
        float4 a = wr[k];
        float4 c0 = w0[k], c1 = w0[k + 32768], c2 = w0[k + 65536], c3 = w0[k + 98304];
        float cx = c0.x + c1.x + c2.x + c3.x;
        float cy = c0.y + c1.y + c2.y + c3.y;
        float cz = c0.z + c1.z + c2.z + c3.z;
        float cw = c0.w + c1.w + c2.w + c3.w;
        acc += a.x * cx + a.y * cy + a.z * cz + a.w * cw;
    }
    for (int o = 32; o; o >>= 1) acc += __shfl_down(acc, o);
    if (lane == 0) cls[b * D_ + i] = acc + bqkv[2 * D_ + i];
}

// ---------------- K7b: res0 = Wo @ cls + bo + ctx ---------------------------
__global__ void k_attn0(const float* __restrict__ Wo, const float* __restrict__ bo,
                        const float* __restrict__ cls, const float* __restrict__ ctx,
                        float* __restrict__ res0) {
    int wid  = (blockIdx.x * 256 + threadIdx.x) >> 6;
    int lane = threadIdx.x & 63;
    int b = wid >> 10, i = wid & 1023;
    const float4* wr = (const float4*)(Wo + (size_t)i * D_);
    const float4* cb = (const float4*)(cls + b * D_);
    float acc = 0.0f;
    for (int k = lane; k < 256; k += 64) {
        float4 a = wr[k], c = cb[k];
        acc += a.x * c.x + a.y * c.y + a.z * c.z + a.w * c.w;
    }
    for (int o = 32; o; o >>= 1) acc += __shfl_down(acc, o);
    if (lane == 0) res0[b * D_ + i] = acc + bo[i] + ctx[b * D_ + i];
}

// ---------------- K7c: LayerNorm of res0 -> context_token_out ---------------
__global__ void k_ln0(const float* __restrict__ res0, const float* __restrict__ gamma,
                      const float* __restrict__ beta, float* __restrict__ out) {
    int b = blockIdx.x, t = threadIdx.x;
    __shared__ float lds[512];
    float v[4];
    float s = 0.0f, sq = 0.0f;
    #pragma unroll
    for (int k = 0; k < 4; ++k) {
        v[k] = res0[b * D_ + t + 256 * k];
        s += v[k]; sq += v[k] * v[k];
    }
    lds[t] = s; lds[256 + t] = sq; __syncthreads();
    for (int o = 128; o; o >>= 1) {
        if (t < o) { lds[t] += lds[t + o]; lds[256 + t] += lds[256 + t + o]; }
        __syncthreads();
    }
    float mu = lds[0] * (1.0f / D_);
    float var = lds[256] * (1.0f / D_) - mu * mu;
    float rstd = rsqrtf(var + EPS_);
    #pragma unroll
    for (int k = 0; k < 4; ++k) {
        int i = t + 256 * k;
        out[(size_t)B_ * D_ * HW_ + b * D_ + i] = (v[k] - mu) * rstd * gamma[i] + beta[i];
    }
}

extern "C" void kernel_launch(void* const* d_in, const int* in_sizes, int n_in,
                              void* d_out, int out_size, void* d_ws, size_t ws_size,
                              hipStream_t stream) {
    const float* x     = (const float*)d_in[0];
    const float* ctx   = (const float*)d_in[1];
    const float* Wqkv  = (const float*)d_in[2];
    const float* bqkv  = (const float*)d_in[3];
    const float* Wo    = (const float*)d_in[4];
    const float* bo    = (const float*)d_in[5];
    const float* gamma = (const float*)d_in[6];
    const float* beta  = (const float*)d_in[7];
    float* out = (float*)d_out;
    float* ws  = (float*)d_ws;

    float* pe   = ws + PE_OFF;
    float* u_t  = ws + UT_OFF;
    float* t_b  = ws + TB_OFF;
    float* scp  = ws + SCP_OFF;  // partial scores; slice 0 becomes probs
    float* sp   = ws + SP_OFF;
    float* qp   = ws + QP_OFF;
    float* wpb  = ws + WP_OFF;   // overlays sp/qp (dead after k_stats)
    float* q0   = ws + Q0_OFF;
    float* vcls = ws + VCLS_OFF;
    float* p0   = ws + P0_OFF;
    float* mu   = ws + MU_OFF;
    float* rs   = ws + RS_OFF;
    float* cls  = ws + CLS_OFF;
    float* r0   = ws + R0_OFF;

    k_pe<<<dim3(8192), dim3(256), 0, stream>>>(pe);
    k_qv<<<dim3(4096), dim3(256), 0, stream>>>(Wqkv, bqkv, ctx, q0, vcls);
    k_u_tb<<<dim3(2176), dim3(256), 0, stream>>>(Wqkv, Wo, bo, q0, vcls, u_t, t_b);
    k_scores2<<<dim3(128, 8), dim3(256), 0, stream>>>(x, pe, u_t, t_b, scp, sp, qp);
    k_softmax2<<<dim3(128), dim3(256), 0, stream>>>(scp, u_t, ctx, p0);
    k_stats<<<dim3(128), dim3(256), 0, stream>>>(sp, qp, mu, rs);
    k_wacc3<<<dim3(256, 8), dim3(256), 0, stream>>>(x, pe, scp, p0, ctx, t_b, mu, rs,
                                                    gamma, beta, wpb, out);
    k_cls2<<<dim3(2048), dim3(256), 0, stream>>>(Wqkv, bqkv, wpb, cls);
    k_attn0<<<dim3(2048), dim3(256), 0, stream>>>(Wo, bo, cls, ctx, r0);
    k_ln0<<<dim3(8), dim3(256), 0, stream>>>(r0, gamma, beta, out);
}

// Round 4
// 609.696 us; speedup vs baseline: 1.1935x; 1.1935x over previous
//
#include <hip/hip_runtime.h>
#include <math.h>

#define B_ 8
#define D_ 1024
#define HW_ 4096
#define NH_ 16
#define EPS_ 1e-5f

// log2(10000) = 13.2877123795...; rate_rev(dp) = 10000^(-2dp/1024)/(2pi)
#define RATE_C (-13.287712379549449f / 512.0f)
#define INV2PI 0.15915494309189535f

// workspace offsets (floats) — total 5,611,648 floats = 22.4 MB
#define UT_OFF   0u          // B*D*NH  u_t[b][d][h] (scale folded)
#define TB_OFF   131072u     // B*D
#define SCP_OFF  139264u     // 8 * B*NH*HW  partial scores
#define SP_OFF   4333568u    // 8 * B*HW
#define QP_OFF   4595712u    // 8 * B*HW
#define PT_OFF   4857856u    // B*HW*NH  probs transposed [b][p][h]
#define W_OFF    5382144u    // B*NH*D
#define Q0_OFF   5513216u    // B*D
#define VCLS_OFF 5521408u    // B*D
#define P0_OFF   5529600u    // B*NH
#define MU_OFF   5529728u    // B*HW
#define RS_OFF   5562496u    // B*HW
#define CLS_OFF  5595264u    // B*D
#define R0_OFF   5603456u    // B*D

// ---------------- K1: q0[b,:] and v_cls[b,:] --------------------------------
__global__ void k_qv(const float* __restrict__ Wqkv, const float* __restrict__ bqkv,
                     const float* __restrict__ ctx,
                     float* __restrict__ q0, float* __restrict__ vcls) {
    int wid  = (blockIdx.x * 256 + threadIdx.x) >> 6;
    int lane = threadIdx.x & 63;
    int isv  = wid >> 13;
    int r    = wid & 8191;
    int b = r >> 10, i = r & 1023;
    int row = isv ? (2 * D_ + i) : i;
    const float4* wr = (const float4*)(Wqkv + (size_t)row * D_);
    const float4* cb = (const float4*)(ctx + b * D_);
    float acc = 0.0f;
    for (int k = lane; k < 256; k += 64) {
        float4 a = wr[k], c = cb[k];
        acc += a.x * c.x + a.y * c.y + a.z * c.z + a.w * c.w;
    }
    for (int o = 32; o; o >>= 1) acc += __shfl_down(acc, o);
    if (lane == 0) {
        float v = acc + bqkv[row];
        if (isv) vcls[b * D_ + i] = v; else q0[b * D_ + i] = v;
    }
}

// ---------------- K2: u_t[b][d][h] (scale folded) and t_b[b][i] -------------
__global__ void k_u_tb(const float* __restrict__ Wqkv,
                       const float* __restrict__ Wo, const float* __restrict__ bo,
                       const float* __restrict__ q0, const float* __restrict__ vcls,
                       float* __restrict__ u_t, float* __restrict__ t_b) {
    if (blockIdx.x < 128) {
        int b = blockIdx.x >> 4, h = blockIdx.x & 15;
        int t = threadIdx.x;
        float a0 = 0, a1 = 0, a2 = 0, a3 = 0;
        const float* q0h = q0 + b * D_ + h * 64;
        for (int j = 0; j < 64; ++j) {
            float qj = q0h[j];
            const float* wr = Wqkv + (size_t)(D_ + h * 64 + j) * D_;
            a0 += qj * wr[t];
            a1 += qj * wr[t + 256];
            a2 += qj * wr[t + 512];
            a3 += qj * wr[t + 768];
        }
        float* ub = u_t + (size_t)(b * D_) * NH_ + h;
        ub[(size_t)t * 16]          = 0.125f * a0;
        ub[(size_t)(t + 256) * 16]  = 0.125f * a1;
        ub[(size_t)(t + 512) * 16]  = 0.125f * a2;
        ub[(size_t)(t + 768) * 16]  = 0.125f * a3;
    } else {
        int wid  = (blockIdx.x - 128) * 4 + (threadIdx.x >> 6);
        int lane = threadIdx.x & 63;
        int b = wid >> 10, i = wid & 1023;
        const float4* wr = (const float4*)(Wo + (size_t)i * D_);
        const float4* vb = (const float4*)(vcls + b * D_);
        float acc = 0.0f;
        for (int k = lane; k < 256; k += 64) {
            float4 a = wr[k], c = vb[k];
            acc += a.x * c.x + a.y * c.y + a.z * c.z + a.w * c.w;
        }
        for (int o = 32; o; o >>= 1) acc += __shfl_down(acc, o);
        if (lane == 0) t_b[b * D_ + i] = acc + bo[i];
    }
}

// ------- KA: partial scores + partial LN stats, pe computed inline ----------
// grid (32 ptiles x 8 dslices, B), block 256 (4 waves). Block: 128 d x 128 p.
// Wave: 32 d (16 d-pairs); lane: 2 p. u_t + t_b staged in LDS.
__global__ __launch_bounds__(256) void k_scoresA(
        const float* __restrict__ x, const float* __restrict__ u_t,
        const float* __restrict__ t_b,
        float* __restrict__ scp, float* __restrict__ sp, float* __restrict__ qp) {
    int tid = threadIdx.x;
    int wave = tid >> 6, lane = tid & 63;
    int b = blockIdx.y;
    int ptile = (blockIdx.x & 31) * 128;
    int ds = blockIdx.x >> 5;            // 0..7 (128 d each)
    int p0 = ptile + lane * 2;

    __shared__ float uts[128 * 16];      // 8 KB
    __shared__ float tbs[128];
    __shared__ float rrev[64];
    __shared__ float red[4][4][128];     // 8 KB
    {
        const float4* src = (const float4*)(u_t + ((size_t)(b * D_ + ds * 128) << 4));
        float4* dst = (float4*)uts;
        dst[tid]       = src[tid];
        dst[tid + 256] = src[tid + 256];
        if (tid < 128) tbs[tid] = t_b[b * D_ + ds * 128 + tid];
        if (tid < 64)  rrev[tid] = exp2f((float)(ds * 64 + tid) * RATE_C) * INV2PI;
    }
    __syncthreads();

    float accA[16], accB[16];
    #pragma unroll
    for (int h = 0; h < 16; ++h) { accA[h] = 0.f; accB[h] = 0.f; }
    float sA = 0.f, sB = 0.f, qA = 0.f, qB = 0.f;
    const float* xb = x + (size_t)b * D_ * HW_ + (size_t)(ds * 128 + wave * 32) * HW_ + p0;
    float fp0 = (float)p0, fp1 = fp0 + 1.0f;

    #pragma unroll 2
    for (int i = 0; i < 16; ++i) {
        int dloc = wave * 32 + i * 2;                  // block-local even d
        float2 xe = *(const float2*)(xb + (size_t)(i * 2) * HW_);
        float2 xo = *(const float2*)(xb + (size_t)(i * 2 + 1) * HW_);
        float rr = rrev[wave * 16 + i];
        float rv0 = fp0 * rr, rv1 = fp1 * rr;
        rv0 -= floorf(rv0); rv1 -= floorf(rv1);
        float sn0 = __builtin_amdgcn_sinf(rv0), cs0 = __builtin_amdgcn_cosf(rv0);
        float sn1 = __builtin_amdgcn_sinf(rv1), cs1 = __builtin_amdgcn_cosf(rv1);
        float xAe = xe.x + sn0, xBe = xe.y + sn1;      // even d: sin
        float xAo = xo.x + cs0, xBo = xo.y + cs1;      // odd d: cos
        float te = tbs[dloc], to = tbs[dloc + 1];
        float rAe = xAe + te, rBe = xBe + te, rAo = xAo + to, rBo = xBo + to;
        sA += rAe + rAo; sB += rBe + rBo;
        qA += rAe * rAe + rAo * rAo; qB += rBe * rBe + rBo * rBo;
        const float4* u4 = (const float4*)(uts + dloc * 16);
        float4 e0 = u4[0], e1 = u4[1], o0 = u4[4], o1 = u4[5];
        accA[0] += e0.x * xAe + o0.x * xAo;  accB[0] += e0.x * xBe + o0.x * xBo;
        accA[1] += e0.y * xAe + o0.y * xAo;  accB[1] += e0.y * xBe + o0.y * xBo;
        accA[2] += e0.z * xAe + o0.z * xAo;  accB[2] += e0.z * xBe + o0.z * xBo;
        accA[3] += e0.w * xAe + o0.w * xAo;  accB[3] += e0.w * xBe + o0.w * xBo;
        accA[4] += e1.x * xAe + o1.x * xAo;  accB[4] += e1.x * xBe + o1.x * xBo;
        accA[5] += e1.y * xAe + o1.y * xAo;  accB[5] += e1.y * xBe + o1.y * xBo;
        accA[6] += e1.z * xAe + o1.z * xAo;  accB[6] += e1.z * xBe + o1.z * xBo;
        accA[7] += e1.w * xAe + o1.w * xAo;  accB[7] += e1.w * xBe + o1.w * xBo;
        float4 e2 = u4[2], e3 = u4[3], o2 = u4[6], o3 = u4[7];
        accA[8]  += e2.x * xAe + o2.x * xAo;  accB[8]  += e2.x * xBe + o2.x * xBo;
        accA[9]  += e2.y * xAe + o2.y * xAo;  accB[9]  += e2.y * xBe + o2.y * xBo;
        accA[10] += e2.z * xAe + o2.z * xAo;  accB[10] += e2.z * xBe + o2.z * xBo;
        accA[11] += e2.w * xAe + o2.w * xAo;  accB[11] += e2.w * xBe + o2.w * xBo;
        accA[12] += e3.x * xAe + o3.x * xAo;  accB[12] += e3.x * xBe + o3.x * xBo;
        accA[13] += e3.y * xAe + o3.y * xAo;  accB[13] += e3.y * xBe + o3.y * xBo;
        accA[14] += e3.z * xAe + o3.z * xAo;  accB[14] += e3.z * xBe + o3.z * xBo;
        accA[15] += e3.w * xAe + o3.w * xAo;  accB[15] += e3.w * xBe + o3.w * xBo;
    }

    // cross-wave reduce 16 h in 4 chunks, then stats
    #pragma unroll 1
    for (int c = 0; c < 4; ++c) {
        if (c) __syncthreads();
        #pragma unroll
        for (int j = 0; j < 4; ++j) {
            red[wave][j][lane * 2]     = accA[c * 4 + j];
            red[wave][j][lane * 2 + 1] = accB[c * 4 + j];
        }
        __syncthreads();
        int j = tid >> 7, p = tid & 127;
        #pragma unroll
        for (int jj = 0; jj < 2; ++jj) {
            int jr = j + jj * 2;
            float s = red[0][jr][p] + red[1][jr][p] + red[2][jr][p] + red[3][jr][p];
            scp[(size_t)ds * 524288 + (size_t)(b * 16 + c * 4 + jr) * HW_ + ptile + p] = s;
        }
    }
    __syncthreads();
    red[wave][0][lane * 2]     = sA;
    red[wave][0][lane * 2 + 1] = sB;
    red[wave][1][lane * 2]     = qA;
    red[wave][1][lane * 2 + 1] = qB;
    __syncthreads();
    if (tid < 128) {
        float S = red[0][0][tid] + red[1][0][tid] + red[2][0][tid] + red[3][0][tid];
        float Q = red[0][1][tid] + red[1][1][tid] + red[2][1][tid] + red[3][1][tid];
        sp[ds * 32768 + b * HW_ + ptile + tid] = S;
        qp[ds * 32768 + b * HW_ + ptile + tid] = Q;
    }
}

// ---------------- K-stats: reduce partial sums -> mu, rstd ------------------
__global__ void k_stats(const float* __restrict__ sp, const float* __restrict__ qp,
                        float* __restrict__ mu_o, float* __restrict__ rs_o) {
    int i = blockIdx.x * 256 + threadIdx.x;
    float S = 0.f, Q = 0.f;
    #pragma unroll
    for (int ds = 0; ds < 8; ++ds) { S += sp[ds * 32768 + i]; Q += qp[ds * 32768 + i]; }
    float mu = S * (1.0f / 1024.0f);
    float var = Q * (1.0f / 1024.0f) - mu * mu;
    mu_o[i] = mu;
    rs_o[i] = rsqrtf(var + EPS_);
}

// ------- KB: softmax over 4097 (sums 8 partials), writes pt[b][p][h] --------
__global__ void k_softmaxT(const float* __restrict__ scp, const float* __restrict__ u_t,
                           const float* __restrict__ ctx,
                           float* __restrict__ pt, float* __restrict__ probs0) {
    int b = blockIdx.x >> 4, h = blockIdx.x & 15;
    int t = threadIdx.x;  // 256
    __shared__ float lds[256];
    float part = 0.0f;
    for (int d = t; d < D_; d += 256)
        part += u_t[(size_t)(b * D_ + d) * 16 + h] * ctx[b * D_ + d];
    lds[t] = part; __syncthreads();
    for (int o = 128; o; o >>= 1) { if (t < o) lds[t] += lds[t + o]; __syncthreads(); }
    float s0 = lds[0];
    __syncthreads();
    size_t row = (size_t)(b * 16 + h) * HW_;
    float4 v[4];
    float m = s0;
    #pragma unroll
    for (int k = 0; k < 4; ++k) {
        float4 vk = make_float4(0.f, 0.f, 0.f, 0.f);
        #pragma unroll
        for (int ds = 0; ds < 8; ++ds) {
            float4 pvk = ((const float4*)(scp + (size_t)ds * 524288 + row))[t + 256 * k];
            vk.x += pvk.x; vk.y += pvk.y; vk.z += pvk.z; vk.w += pvk.w;
        }
        v[k] = vk;
        m = fmaxf(m, fmaxf(fmaxf(vk.x, vk.y), fmaxf(vk.z, vk.w)));
    }
    lds[t] = m; __syncthreads();
    for (int o = 128; o; o >>= 1) { if (t < o) lds[t] = fmaxf(lds[t], lds[t + o]); __syncthreads(); }
    m = lds[0];
    __syncthreads();
    float zs = 0.0f;
    #pragma unroll
    for (int k = 0; k < 4; ++k) {
        v[k].x = expf(v[k].x - m); v[k].y = expf(v[k].y - m);
        v[k].z = expf(v[k].z - m); v[k].w = expf(v[k].w - m);
        zs += v[k].x + v[k].y + v[k].z + v[k].w;
    }
    float e0 = expf(s0 - m);
    lds[t] = zs; __syncthreads();
    for (int o = 128; o; o >>= 1) { if (t < o) lds[t] += lds[t + o]; __syncthreads(); }
    float inv = 1.0f / (lds[0] + e0);
    float* ptb = pt + (size_t)b * HW_ * 16 + h;
    #pragma unroll
    for (int k = 0; k < 4; ++k) {
        int p = 4 * (t + 256 * k);
        ptb[(size_t)(p + 0) * 16] = v[k].x * inv;
        ptb[(size_t)(p + 1) * 16] = v[k].y * inv;
        ptb[(size_t)(p + 2) * 16] = v[k].z * inv;
        ptb[(size_t)(p + 3) * 16] = v[k].w * inv;
    }
    if (t == 0) probs0[b * 16 + h] = e0 * inv;
}

// ------- KC: fused w-accumulate + LN feature-map write, pe inline -----------
// grid (256 dgroups, B), block 256 (4 waves). Wave: 1 d-row; lane: float4 p.
__global__ __launch_bounds__(256) void k_waccB(
        const float* __restrict__ x, const float* __restrict__ pt,
        const float* __restrict__ p0v, const float* __restrict__ ctx,
        const float* __restrict__ t_b, const float* __restrict__ mu_i,
        const float* __restrict__ rs_i, const float* __restrict__ gamma,
        const float* __restrict__ beta,
        float* __restrict__ w, float* __restrict__ out) {
    int wave = threadIdx.x >> 6, lane = threadIdx.x & 63;
    int b = blockIdx.y;
    int d = blockIdx.x * 4 + wave;
    float tb = t_b[b * D_ + d], g = gamma[d], be = beta[d];
    int odd = d & 1;
    float rr = exp2f((float)(d >> 1) * RATE_C) * INV2PI;
    const float* xr  = x + (size_t)b * D_ * HW_ + (size_t)d * HW_;
    const float* ptb = pt + (size_t)b * HW_ * 16;
    const float* mub = mu_i + b * HW_;
    const float* rsb = rs_i + b * HW_;
    float* or_ = out + (size_t)b * D_ * HW_ + (size_t)d * HW_;
    float acc[16];
    #pragma unroll
    for (int h = 0; h < 16; ++h) acc[h] = 0.f;

    #pragma unroll 1
    for (int it = 0; it < 16; ++it) {
        int p = it * 256 + lane * 4;
        float4 xv = *(const float4*)(xr + p);
        float4 m4 = *(const float4*)(mub + p);
        float4 r4 = *(const float4*)(rsb + p);
        float rv0 = (float)p * rr;
        float rv1 = rv0 + rr, rv2 = rv1 + rr, rv3 = rv2 + rr;
        rv0 -= floorf(rv0); rv1 -= floorf(rv1); rv2 -= floorf(rv2); rv3 -= floorf(rv3);
        float pe0 = odd ? __builtin_amdgcn_cosf(rv0) : __builtin_amdgcn_sinf(rv0);
        float pe1 = odd ? __builtin_amdgcn_cosf(rv1) : __builtin_amdgcn_sinf(rv1);
        float pe2 = odd ? __builtin_amdgcn_cosf(rv2) : __builtin_amdgcn_sinf(rv2);
        float pe3 = odd ? __builtin_amdgcn_cosf(rv3) : __builtin_amdgcn_sinf(rv3);
        float xc0 = xv.x + pe0, xc1 = xv.y + pe1, xc2 = xv.z + pe2, xc3 = xv.w + pe3;
        float4 o4;
        o4.x = (xc0 + tb - m4.x) * r4.x * g + be;
        o4.y = (xc1 + tb - m4.y) * r4.y * g + be;
        o4.z = (xc2 + tb - m4.z) * r4.z * g + be;
        o4.w = (xc3 + tb - m4.w) * r4.w * g + be;
        *(float4*)(or_ + p) = o4;
        const float4* q4 = (const float4*)(ptb + (size_t)p * 16);
        #pragma unroll
        for (int j = 0; j < 4; ++j) {
            float xcj = (j == 0) ? xc0 : (j == 1) ? xc1 : (j == 2) ? xc2 : xc3;
            float4 a0 = q4[j * 4 + 0], a1 = q4[j * 4 + 1];
            float4 a2 = q4[j * 4 + 2], a3 = q4[j * 4 + 3];
            acc[0]  += a0.x * xcj; acc[1]  += a0.y * xcj;
            acc[2]  += a0.z * xcj; acc[3]  += a0.w * xcj;
            acc[4]  += a1.x * xcj; acc[5]  += a1.y * xcj;
            acc[6]  += a1.z * xcj; acc[7]  += a1.w * xcj;
            acc[8]  += a2.x * xcj; acc[9]  += a2.y * xcj;
            acc[10] += a2.z * xcj; acc[11] += a2.w * xcj;
            acc[12] += a3.x * xcj; acc[13] += a3.y * xcj;
            acc[14] += a3.z * xcj; acc[15] += a3.w * xcj;
        }
    }
    #pragma unroll
    for (int h = 0; h < 16; ++h) {
        float v = acc[h];
        for (int o = 32; o; o >>= 1) v += __shfl_down(v, o);
        acc[h] = v;
    }
    if (lane == 0) {
        float cx = ctx[b * D_ + d];
        #pragma unroll
        for (int h = 0; h < 16; ++h)
            w[(size_t)(b * 16 + h) * D_ + d] = acc[h] + p0v[b * 16 + h] * cx;
    }
}

// ---------------- K7a: cls[b][i] = Wv[i,:] . w[b][i>>6][:] + bv -------------
__global__ void k_cls(const float* __restrict__ Wqkv, const float* __restrict__ bqkv,
                      const float* __restrict__ w, float* __restrict__ cls) {
    int wid  = (blockIdx.x * 256 + threadIdx.x) >> 6;
    int lane = threadIdx.x & 63;
    int b = wid >> 10, i = wid & 1023, h = i >> 6;
    const float4* wr = (const float4*)(Wqkv + (size_t)(2 * D_ + i) * D_);
    const float4* wb = (const float4*)(w + (size_t)(b * 16 + h) * D_);
    float acc = 0.0f;
    for (int k = lane; k < 256; k += 64) {
        float4 a = wr[k], c = wb[k];
        acc += a.x * c.x + a.y * c.y + a.z * c.z + a.w * c.w;
    }
    for (int o = 32; o; o >>= 1) acc += __shfl_down(acc, o);
    if (lane == 0) cls[b * D_ + i] = acc + bqkv[2 * D_ + i];
}

// ---------------- K7b: res0 = Wo @ cls + bo + ctx ---------------------------
__global__ void k_attn0(const float* __restrict__ Wo, const float* __restrict__ bo,
                        const float* __restrict__ cls, const float* __restrict__ ctx,
                        float* __restrict__ res0) {
    int wid  = (blockIdx.x * 256 + threadIdx.x) >> 6;
    int lane = threadIdx.x & 63;
    int b = wid >> 10, i = wid & 1023;
    const float4* wr = (const float4*)(Wo + (size_t)i * D_);
    const float4* cb = (const float4*)(cls + b * D_);
    float acc = 0.0f;
    for (int k = lane; k < 256; k += 64) {
        float4 a = wr[k], c = cb[k];
        acc += a.x * c.x + a.y * c.y + a.z * c.z + a.w * c.w;
    }
    for (int o = 32; o; o >>= 1) acc += __shfl_down(acc, o);
    if (lane == 0) res0[b * D_ + i] = acc + bo[i] + ctx[b * D_ + i];
}

// ---------------- K7c: LayerNorm of res0 -> context_token_out ---------------
__global__ void k_ln0(const float* __restrict__ res0, const float* __restrict__ gamma,
                      const float* __restrict__ beta, float* __restrict__ out) {
    int b = blockIdx.x, t = threadIdx.x;
    __shared__ float lds[512];
    float v[4];
    float s = 0.0f, sq = 0.0f;
    #pragma unroll
    for (int k = 0; k < 4; ++k) {
        v[k] = res0[b * D_ + t + 256 * k];
        s += v[k]; sq += v[k] * v[k];
    }
    lds[t] = s; lds[256 + t] = sq; __syncthreads();
    for (int o = 128; o; o >>= 1) {
        if (t < o) { lds[t] += lds[t + o]; lds[256 + t] += lds[256 + t + o]; }
        __syncthreads();
    }
    float mu = lds[0] * (1.0f / D_);
    float var = lds[256] * (1.0f / D_) - mu * mu;
    float rstd = rsqrtf(var + EPS_);
    #pragma unroll
    for (int k = 0; k < 4; ++k) {
        int i = t + 256 * k;
        out[(size_t)B_ * D_ * HW_ + b * D_ + i] = (v[k] - mu) * rstd * gamma[i] + beta[i];
    }
}

extern "C" void kernel_launch(void* const* d_in, const int* in_sizes, int n_in,
                              void* d_out, int out_size, void* d_ws, size_t ws_size,
                              hipStream_t stream) {
    const float* x     = (const float*)d_in[0];
    const float* ctx   = (const float*)d_in[1];
    const float* Wqkv  = (const float*)d_in[2];
    const float* bqkv  = (const float*)d_in[3];
    const float* Wo    = (const float*)d_in[4];
    const float* bo    = (const float*)d_in[5];
    const float* gamma = (const float*)d_in[6];
    const float* beta  = (const float*)d_in[7];
    float* out = (float*)d_out;
    float* ws  = (float*)d_ws;

    float* u_t  = ws + UT_OFF;
    float* t_b  = ws + TB_OFF;
    float* scp  = ws + SCP_OFF;
    float* sp   = ws + SP_OFF;
    float* qp   = ws + QP_OFF;
    float* pt   = ws + PT_OFF;
    float* w    = ws + W_OFF;
    float* q0   = ws + Q0_OFF;
    float* vcls = ws + VCLS_OFF;
    float* p0   = ws + P0_OFF;
    float* mu   = ws + MU_OFF;
    float* rs   = ws + RS_OFF;
    float* cls  = ws + CLS_OFF;
    float* r0   = ws + R0_OFF;

    k_qv<<<dim3(4096), dim3(256), 0, stream>>>(Wqkv, bqkv, ctx, q0, vcls);
    k_u_tb<<<dim3(2176), dim3(256), 0, stream>>>(Wqkv, Wo, bo, q0, vcls, u_t, t_b);
    k_scoresA<<<dim3(256, 8), dim3(256), 0, stream>>>(x, u_t, t_b, scp, sp, qp);
    k_stats<<<dim3(128), dim3(256), 0, stream>>>(sp, qp, mu, rs);
    k_softmaxT<<<dim3(128), dim3(256), 0, stream>>>(scp, u_t, ctx, pt, p0);
    k_waccB<<<dim3(256, 8), dim3(256), 0, stream>>>(x, pt, p0, ctx, t_b, mu, rs,
                                                    gamma, beta, w, out);
    k_cls<<<dim3(2048), dim3(256), 0, stream>>>(Wqkv, bqkv, w, cls);
    k_attn0<<<dim3(2048), dim3(256), 0, stream>>>(Wo, bo, cls, ctx, r0);
    k_ln0<<<dim3(8), dim3(256), 0, stream>>>(r0, gamma, beta, out);
}